// Round 4
// baseline (224.278 us; speedup 1.0000x reference)
//
#include <hip/hip_runtime.h>

// Multi-head causal attention fwd, B=2 S=2048 D=1024 H=16 DK=DV=64.
// fp32 I/O; internal bf16 MFMA pipeline.
// 4 dispatches: convert, fused-QKV gemm, flash-attn (S^T form), final gemm.

typedef __bf16 bf16;
typedef __bf16 bf16x8 __attribute__((ext_vector_type(8)));
typedef __bf16 bf16x4 __attribute__((ext_vector_type(4)));
typedef float  f32x4  __attribute__((ext_vector_type(4)));

#define B_  2
#define S_  2048
#define D_  1024
#define H_  16
#define HD  64
#define NEG_BIG (-3.0e38f)
#define SCALE_LOG2E 0.1803368801111204f   // (1/8) * log2(e)

__device__ __forceinline__ void lds16(const void* g, void* l) {
    __builtin_amdgcn_global_load_lds((const __attribute__((address_space(1))) void*)g,
                                     (__attribute__((address_space(3))) void*)l, 16, 0, 0);
}

__device__ __forceinline__ f32x4 mfma16(bf16x8 a, bf16x8 b, f32x4 c) {
    return __builtin_amdgcn_mfma_f32_16x16x32_bf16(a, b, c, 0, 0, 0);
}

// ---------------- fp32 -> bf16 convert pre-pass ----------------
__global__ __launch_bounds__(256) void convert_k(const float* __restrict__ X,
                                                 const float* __restrict__ wq,
                                                 const float* __restrict__ wk,
                                                 const float* __restrict__ wv,
                                                 const float* __restrict__ wo,
                                                 bf16* __restrict__ dst) {
    const int gid = blockIdx.x * 256 + threadIdx.x;
    const int i   = gid * 4;
    const float* src;
    int off;
    if      (i < (4 << 20)) { src = X;  off = 0; }
    else if (i < (5 << 20)) { src = wq; off = 4 << 20; }
    else if (i < (6 << 20)) { src = wk; off = 5 << 20; }
    else if (i < (7 << 20)) { src = wv; off = 6 << 20; }
    else                    { src = wo; off = 7 << 20; }
    const float4 v = *(const float4*)(src + (i - off));
    bf16x4 p;
    p[0] = (bf16)v.x; p[1] = (bf16)v.y; p[2] = (bf16)v.z; p[3] = (bf16)v.w;
    *(bf16x4*)(dst + i) = p;
}

// ---------------- fused QKV GEMM ----------------
__global__ __launch_bounds__(256) void gemm_qkv(const bf16* __restrict__ A,
                                                const bf16* __restrict__ Wq,
                                                const bf16* __restrict__ Wk,
                                                const bf16* __restrict__ Wv,
                                                const float* __restrict__ bq,
                                                const float* __restrict__ bk,
                                                const float* __restrict__ bv,
                                                bf16* __restrict__ Qw,
                                                bf16* __restrict__ Kw,
                                                bf16* __restrict__ Vw) {
    constexpr int K = 1024;
    __shared__ bf16 sA[128 * 32];
    __shared__ bf16 sB[128 * 32];
    const int tid  = threadIdx.x;
    const int l15  = tid & 15;
    const int quad = (tid & 63) >> 4;
    const int wid  = tid >> 6;
    const int seg  = blockIdx.x >> 3;
    const int bn   = blockIdx.x & 7;
    const int bm   = blockIdx.y;
    const int wm   = (wid >> 1) * 64;
    const int wn   = (wid & 1) * 64;

    const bf16* W    = (seg == 0) ? Wq : (seg == 1) ? Wk : Wv;
    const float* bias = (seg == 0) ? bq : (seg == 1) ? bk : bv;

    const bf16* Ab = A + (size_t)bm * 128 * K;
    const bf16* Wb = W + (size_t)bn * 128 * K;

    f32x4 acc[4][4] = {};

    for (int k0 = 0; k0 < K; k0 += 32) {
        __syncthreads();
        #pragma unroll
        for (int it = 0; it < 2; ++it) {
            int c = it * 256 + tid;
            int row = c >> 2, c8 = c & 3;
            lds16(Ab + row * K + k0 + c8 * 8, (char*)sA + c * 16);
            lds16(Wb + row * K + k0 + c8 * 8, (char*)sB + c * 16);
        }
        __syncthreads();
        bf16x8 af[4], bfr[4];
        #pragma unroll
        for (int i = 0; i < 4; ++i)
            af[i] = *(const bf16x8*)&sA[(wm + i * 16 + l15) * 32 + quad * 8];
        #pragma unroll
        for (int i = 0; i < 4; ++i)
            bfr[i] = *(const bf16x8*)&sB[(wn + i * 16 + l15) * 32 + quad * 8];
        #pragma unroll
        for (int mi = 0; mi < 4; ++mi)
            #pragma unroll
            for (int ni = 0; ni < 4; ++ni)
                acc[mi][ni] = mfma16(af[mi], bfr[ni], acc[mi][ni]);
    }

    #pragma unroll
    for (int ni = 0; ni < 4; ++ni) {
        const int n  = bn * 128 + wn + ni * 16 + l15;
        const float bv_ = bias[n];
        const int h = n >> 6;
        #pragma unroll
        for (int mi = 0; mi < 4; ++mi) {
            const int m0 = bm * 128 + wm + mi * 16 + quad * 4;
            if (seg == 2) {   // V transposed: [B,H,64,S]
                const int dv = n & 63;
                const int b = m0 >> 11, s = m0 & 2047;
                bf16x4 pack;
                #pragma unroll
                for (int r = 0; r < 4; ++r) pack[r] = (bf16)(acc[mi][ni][r] + bv_);
                *(bf16x4*)&Vw[(((size_t)(b * H_ + h) * HD + dv) << 11) + s] = pack;
            } else {          // Q,K: [B,H,S,64]
                bf16* C = (seg == 0) ? Qw : Kw;
                const int dk = n & 63;
                #pragma unroll
                for (int r = 0; r < 4; ++r) {
                    const int m = m0 + r, b = m >> 11, s = m & 2047;
                    C[(((size_t)(b * H_ + h) << 11) + s) * HD + dk] =
                        (bf16)(acc[mi][ni][r] + bv_);
                }
            }
        }
    }
}

// ---------------- final GEMM: out[M,N] fp32 = A @ Wo^T + bias ----------------
__global__ __launch_bounds__(256) void gemm_fin(const bf16* __restrict__ A,
                                                const bf16* __restrict__ W,
                                                const float* __restrict__ bias,
                                                float* __restrict__ C) {
    constexpr int N = 1024, K = 1024;
    __shared__ bf16 sA[128 * 32];
    __shared__ bf16 sB[128 * 32];
    const int tid  = threadIdx.x;
    const int l15  = tid & 15;
    const int quad = (tid & 63) >> 4;
    const int wid  = tid >> 6;
    const int bm   = blockIdx.x >> 3;
    const int bn   = blockIdx.x & 7;
    const int wm   = (wid >> 1) * 64;
    const int wn   = (wid & 1) * 64;

    const bf16* Ab = A + (size_t)bm * 128 * K;
    const bf16* Wb = W + (size_t)bn * 128 * K;

    f32x4 acc[4][4] = {};

    for (int k0 = 0; k0 < K; k0 += 32) {
        __syncthreads();
        #pragma unroll
        for (int it = 0; it < 2; ++it) {
            int c = it * 256 + tid;
            int row = c >> 2, c8 = c & 3;
            lds16(Ab + row * K + k0 + c8 * 8, (char*)sA + c * 16);
            lds16(Wb + row * K + k0 + c8 * 8, (char*)sB + c * 16);
        }
        __syncthreads();
        bf16x8 af[4], bfr[4];
        #pragma unroll
        for (int i = 0; i < 4; ++i)
            af[i] = *(const bf16x8*)&sA[(wm + i * 16 + l15) * 32 + quad * 8];
        #pragma unroll
        for (int i = 0; i < 4; ++i)
            bfr[i] = *(const bf16x8*)&sB[(wn + i * 16 + l15) * 32 + quad * 8];
        #pragma unroll
        for (int mi = 0; mi < 4; ++mi)
            #pragma unroll
            for (int ni = 0; ni < 4; ++ni)
                acc[mi][ni] = mfma16(af[mi], bfr[ni], acc[mi][ni]);
    }

    #pragma unroll
    for (int ni = 0; ni < 4; ++ni) {
        const int n  = bn * 128 + wn + ni * 16 + l15;
        const float bv = bias[n];
        #pragma unroll
        for (int mi = 0; mi < 4; ++mi) {
            const int m0 = bm * 128 + wm + mi * 16 + quad * 4;
            #pragma unroll
            for (int r = 0; r < 4; ++r)
                C[(size_t)(m0 + r) * N + n] = acc[mi][ni][r] + bv;
        }
    }
}

// ---------------- Flash attention, S^T formulation ----------------
// 512 threads (8 waves), 128-q tile/block, each wave owns 16 q (lane l15 = q).
// S^T = K*Q^T -> C-layout col=q: softmax is per-lane (2 wave shuffles),
// P written as [q][key] rows (b64, padded stride 272B), PV reads b128 A-frags.
// K/V register-staged: next tile's global loads overlap current compute.
#define PSTRIDE 136   // bf16 elems per sP row (272 B = 17*16B)
__global__ __launch_bounds__(512, 4) void attn_k(const bf16* __restrict__ Q,
                                                 const bf16* __restrict__ K,
                                                 const bf16* __restrict__ Vt,
                                                 const float* __restrict__ pmask,
                                                 bf16* __restrict__ Aout) {
    __shared__ bf16 sK_[2 * 128 * 32];    // 16K [kk][krow][32]
    __shared__ bf16 sV[4 * 64 * 32];      // 16K [kc][dv][32]  (V^T)
    __shared__ bf16 sP[128 * PSTRIDE];    // 34K P as [q][key], padded rows
    const int tid  = threadIdx.x;
    const int l15  = tid & 15;
    const int quad = (tid & 63) >> 4;
    const int wid  = tid >> 6;            // 0..7
    const int idx  = blockIdx.x >> 5;
    const int qt   = (idx < 8) ? (15 - idx) : (idx - 8);
    const int bh   = blockIdx.x & 31;
    const int b    = bh >> 4;
    const int h    = bh & 15;

    // ---- stage Q (one-time) into sP region as contiguous planes [2][128][32]
    const bf16* Qg = Q + ((size_t)bh * S_ + qt * 128) * HD;
    #pragma unroll
    for (int it = 0; it < 2; ++it) {
        int c = it * 512 + tid;
        int pl = c >> 9, row = (c >> 2) & 127, c8 = c & 3;
        lds16(Qg + row * HD + pl * 32 + c8 * 8, (char*)sP + c * 16);
    }
    // ---- register-stage K/V for kt=0 (in flight across the barrier)
    bf16x8 kreg[2], vreg[2];
    {
        const bf16* Kg = K  + (size_t)bh * S_ * HD;
        const bf16* Vg = Vt + (size_t)bh * HD * S_;
        #pragma unroll
        for (int it = 0; it < 2; ++it) {
            int c = it * 512 + tid;
            int pl = c >> 9, row = (c >> 2) & 127, c8 = c & 3;
            kreg[it] = *(const bf16x8*)(Kg + row * HD + pl * 32 + c8 * 8);
            int kc = c >> 8, dv = (c >> 2) & 63;
            vreg[it] = *(const bf16x8*)(Vg + dv * S_ + kc * 32 + c8 * 8);
        }
    }
    __syncthreads();
    bf16x8 aq[2];   // Q B-fragment: lane n=q=wid*16+l15, k=kk*32+quad*8+j
    #pragma unroll
    for (int kk = 0; kk < 2; ++kk)
        aq[kk] = *(const bf16x8*)&sP[(kk * 128 + wid * 16 + l15) * 32 + quad * 8];

    float m_i = NEG_BIG, l_i = 0.f;
    f32x4 o[4] = {};
    const int qg = wid * 16 + l15;        // this lane's q within the 128-tile

    for (int kt = 0; kt <= qt; ++kt) {
        __syncthreads();                  // prev iter's sK/sV/sP reads done
        // staged regs -> LDS (waits the in-flight global loads)
        #pragma unroll
        for (int it = 0; it < 2; ++it) {
            int c = it * 512 + tid;
            *(bf16x8*)((char*)sK_ + c * 16) = kreg[it];
            *(bf16x8*)((char*)sV  + c * 16) = vreg[it];
        }
        // issue next tile's loads; latency hidden under this iter's compute
        if (kt < qt) {
            const bf16* Kg = K  + ((size_t)bh * S_ + (kt + 1) * 128) * HD;
            const bf16* Vg = Vt + (size_t)bh * HD * S_ + (kt + 1) * 128;
            #pragma unroll
            for (int it = 0; it < 2; ++it) {
                int c = it * 512 + tid;
                int pl = c >> 9, row = (c >> 2) & 127, c8 = c & 3;
                kreg[it] = *(const bf16x8*)(Kg + row * HD + pl * 32 + c8 * 8);
                int kc = c >> 8, dv = (c >> 2) & 63;
                vreg[it] = *(const bf16x8*)(Vg + dv * S_ + kc * 32 + c8 * 8);
            }
        }
        __syncthreads();

        // S^T = K*Q^T: lane holds key=tc*16+quad*4+r (r=reg), q=qg
        f32x4 s[8] = {};
        #pragma unroll
        for (int tc = 0; tc < 8; ++tc) {
            #pragma unroll
            for (int kk = 0; kk < 2; ++kk) {
                bf16x8 kb = *(const bf16x8*)
                    &sK_[(kk * 128 + tc * 16 + l15) * 32 + quad * 8];
                s[tc] = mfma16(kb, aq[kk], s[tc]);   // A=K, B=Q -> S^T
            }
        }

        // scale (log2 domain) + padding + causal
        const bool diag = (kt == qt);
        #pragma unroll
        for (int tc = 0; tc < 8; ++tc) {
            const float4 pv = *(const float4*)
                &pmask[b * S_ + kt * 128 + tc * 16 + quad * 4];
            #pragma unroll
            for (int r = 0; r < 4; ++r) {
                float v = s[tc][r] * SCALE_LOG2E;
                if (((const float*)&pv)[r] > 0.f) v = NEG_BIG;
                if (diag && (tc * 16 + quad * 4 + r > qg)) v = NEG_BIG;
                s[tc][r] = v;
            }
        }

        // per-lane online softmax (one q per lane, 32 scores in-register)
        float rm = s[0][0];
        #pragma unroll
        for (int tc = 0; tc < 8; ++tc)
            #pragma unroll
            for (int r = 0; r < 4; ++r) rm = fmaxf(rm, s[tc][r]);
        rm = fmaxf(rm, __shfl_xor(rm, 16));
        rm = fmaxf(rm, __shfl_xor(rm, 32));
        const float mn    = fmaxf(m_i, rm);
        const float alpha = exp2f(m_i - mn);
        m_i = mn;
        float rs = 0.f;
        #pragma unroll
        for (int tc = 0; tc < 8; ++tc)
            #pragma unroll
            for (int r = 0; r < 4; ++r) {
                float p = exp2f(s[tc][r] - mn);
                s[tc][r] = p;
                rs += p;
            }
        rs += __shfl_xor(rs, 16);
        rs += __shfl_xor(rs, 32);
        l_i = l_i * alpha + rs;

        // P -> sP[q][key]: 4 consecutive keys per lane = one b64 store
        #pragma unroll
        for (int tc = 0; tc < 8; ++tc) {
            bf16x4 pk;
            #pragma unroll
            for (int r = 0; r < 4; ++r) pk[r] = (bf16)s[tc][r];
            *(bf16x4*)&sP[qg * PSTRIDE + tc * 16 + quad * 4] = pk;
        }

        // rescale O (rows = quad*4+r); alpha lives at lane l15=q -> shuffle
        #pragma unroll
        for (int r = 0; r < 4; ++r) {
            float ar = __shfl(alpha, quad * 4 + r, 16);
            #pragma unroll
            for (int vc = 0; vc < 4; ++vc) o[vc][r] *= ar;
        }
        __syncthreads();                  // sP visible

        // O += P*V  (A=P rows q, B=V^T)
        #pragma unroll
        for (int kc = 0; kc < 4; ++kc) {
            bf16x8 ap = *(const bf16x8*)
                &sP[(wid * 16 + l15) * PSTRIDE + kc * 32 + quad * 8];
            #pragma unroll
            for (int vc = 0; vc < 4; ++vc) {
                bf16x8 bv = *(const bf16x8*)
                    &sV[(kc * 64 + vc * 16 + l15) * 32 + quad * 8];
                o[vc] = mfma16(ap, bv, o[vc]);
            }
        }
    }

    // epilogue: O rows q=wid*16+quad*4+r, col dv=vc*16+l15
    const float inv = 1.f / l_i;
    #pragma unroll
    for (int r = 0; r < 4; ++r) {
        float ir = __shfl(inv, quad * 4 + r, 16);
        int q = qt * 128 + wid * 16 + quad * 4 + r;
        size_t base = ((size_t)b * S_ + q) * D_ + h * HD;
        #pragma unroll
        for (int vc = 0; vc < 4; ++vc)
            Aout[base + vc * 16 + l15] = (bf16)(o[vc][r] * ir);
    }
}

extern "C" void kernel_launch(void* const* d_in, const int* in_sizes, int n_in,
                              void* d_out, int out_size, void* d_ws, size_t ws_size,
                              hipStream_t stream) {
    const float* X   = (const float*)d_in[0];
    const float* pm  = (const float*)d_in[1];
    const float* wq  = (const float*)d_in[2];
    const float* bq  = (const float*)d_in[3];
    const float* wk  = (const float*)d_in[4];
    const float* bk  = (const float*)d_in[5];
    const float* wv  = (const float*)d_in[6];
    const float* bvb = (const float*)d_in[7];
    const float* wo  = (const float*)d_in[8];
    const float* bo  = (const float*)d_in[9];
    float* out = (float*)d_out;

    char* ws = (char*)d_ws;
    bf16* Xb  = (bf16*)(ws);                  // 4M elems  8 MiB
    bf16* Wqb = (bf16*)(ws + (8u  << 20));    // 1M elems  2 MiB each
    bf16* Wkb = (bf16*)(ws + (10u << 20));
    bf16* Wvb = (bf16*)(ws + (12u << 20));
    bf16* Wob = (bf16*)(ws + (14u << 20));
    bf16* Qw  = (bf16*)(ws + (16u << 20));    // [B,H,S,64]  8 MiB
    bf16* Kw  = (bf16*)(ws + (24u << 20));    // [B,H,S,64]  8 MiB
    bf16* Vw  = (bf16*)(ws + (32u << 20));    // [B,H,64,S]  8 MiB
    bf16* Aw  = (bf16*)(ws + (40u << 20));    // [B*S, 1024] 8 MiB

    convert_k<<<dim3(8192), dim3(256), 0, stream>>>(X, wq, wk, wv, wo, Xb);
    gemm_qkv<<<dim3(24, 32), dim3(256), 0, stream>>>(Xb, Wqb, Wkb, Wvb,
                                                     bq, bk, bvb, Qw, Kw, Vw);
    attn_k<<<dim3(512), dim3(512), 0, stream>>>(Qw, Kw, Vw, pm, Aw);
    gemm_fin<<<dim3(256), dim3(256), 0, stream>>>(Aw, Wob, bo, out);
}